// Round 1
// baseline (65.718 us; speedup 1.0000x reference)
//
#include <hip/hip_runtime.h>
#include <hip/hip_bf16.h>
#include <stdint.h>

// KAN layer: out[n,o] = sum_j w[o,j] * spline(x[n,j]; coeffs[o,j,:]) + bias[o]
// N=1024, D_IN=128, D_OUT=128, K=8, Catmull-Rom, uniform grid [-1,1].
// fp32 in/out (proven R1/R2/R4).
//
// R13: the measured window = 40.9us ws-poison fill (82% HBM peak, fixed) +
// ~12us graph ops (fixed) + kernel. R12's single kernel recomputed the
// bf16 basis tile per o-block (8x redundant) and W' = w*coeffs per n-block
// (64x redundant): ~2.1M phase-1 tasks where 147K are unique -> 93% of its
// VALU was waste. Split into:
//   kan_pre: 147,456 unique tasks -> ws  (basis 2MB + W' 256KB, bf16,
//            [row][j][k] linear layout; blocks 0..127 basis, 128..143 W',
//            no intra-block divergence)
//   kan_mm:  pure GEMM consumer. Per wave: 2 K-steps of direct global->VGPR
//            16B fragment loads (L2/LLC-resident; no LDS staging, no
//            swizzle, no pre-MFMA barrier) + MFMA, then the R12-verified
//            16-way LDS reduce (sC 16KB only).
// Numerics identical to R12 (same clip/trunc/bf16-RNE path).
//
// MFMA 16x16x32 bf16 (R5..R12-verified): A/B-frag lane (mo=lane&15,
// q=lane>>4) holds [mo][k=32S+8q+kk]; C/D: col=lane&15, row=(lane>>4)*4+reg.

#define DIN 128
#define DOUT 128
#define KTOT 1024

typedef unsigned int u32;
typedef unsigned short u16;
typedef __attribute__((ext_vector_type(8))) short bf16x8;
typedef __attribute__((ext_vector_type(4))) float f32x4;

union H8 { u16 s[8]; uint4 v; };

__device__ __forceinline__ u16 f2b(float f) {
    union { __hip_bfloat16 h; u16 u; } c;
    c.h = __float2bfloat16(f);   // RNE
    return c.u;
}

// ---- Kernel 1: precompute basis[n][j][:] and W'[o][j][:] into ws ----
// t < nBasis       : basis task (n*128+j), 8 bf16 -> gBas + t*8
// t - nBasis < 16K : W' task   (o*128+j), 8 bf16 -> gWp + u*8
__global__ __launch_bounds__(1024) void kan_pre(
    const float* __restrict__ x, const float* __restrict__ coeffs,
    const float* __restrict__ weights, u16* __restrict__ gBas,
    u16* __restrict__ gWp, int nBasis)
{
    const int t = blockIdx.x * 1024 + threadIdx.x;
    if (t < nBasis) {
        float xv = x[t];                            // coalesced
        xv = fminf(fmaxf(xv, -1.0f), 1.0f);
        const float tt = (xv + 1.0f) * 3.5f;        // h = 2/7
        int idx = (int)tt; idx = idx > 6 ? 6 : idx; // tt>=0: trunc==floor
        const float u = tt - (float)idx;
        const float u2 = u * u, u3 = u2 * u;
        const float b0 = 0.5f * (-u3 + 2.0f * u2 - u);
        const float b1 = 0.5f * (3.0f * u3 - 5.0f * u2 + 2.0f);
        const float b2 = 0.5f * (-3.0f * u3 + 4.0f * u2 + u);
        const float b3 = 0.5f * (u3 - u2);
        float r[8];
        #pragma unroll
        for (int k = 0; k < 8; ++k) r[k] = 0.0f;
        const int i0 = idx > 0 ? idx - 1 : 0;       // accumulate = clip fix
        const int i3 = idx < 6 ? idx + 2 : 7;
        r[i0] += b0; r[idx] += b1; r[idx + 1] += b2; r[i3] += b3;
        H8 h;
        #pragma unroll
        for (int k = 0; k < 8; ++k) h.s[k] = f2b(r[k]);
        *(uint4*)(gBas + (size_t)t * 8) = h.v;      // coalesced 16B
    } else {
        const int u = t - nBasis;                   // o*128 + j
        if (u < DOUT * DIN) {
            const float wv = weights[u];
            const float4 c0 = *(const float4*)(coeffs + (size_t)u * 8);
            const float4 c1 = *(const float4*)(coeffs + (size_t)u * 8 + 4);
            H8 h;
            h.s[0] = f2b(c0.x * wv); h.s[1] = f2b(c0.y * wv);
            h.s[2] = f2b(c0.z * wv); h.s[3] = f2b(c0.w * wv);
            h.s[4] = f2b(c1.x * wv); h.s[5] = f2b(c1.y * wv);
            h.s[6] = f2b(c1.z * wv); h.s[7] = f2b(c1.w * wv);
            *(uint4*)(gWp + (size_t)u * 8) = h.v;
        }
    }
}

// ---- Kernel 2: GEMM consumer. 16 waves = 16-way K-split, 2 steps each ----
__global__ __launch_bounds__(1024) void kan_mm(
    const u16* __restrict__ gBas, const u16* __restrict__ gWp,
    const float* __restrict__ bias, float* __restrict__ out)
{
    __shared__ __align__(16) float sC[16 * 256];    // 16 KB partials only

    const int tid  = threadIdx.x;
    const int wave = tid >> 6;                      // 0..15
    const int lane = tid & 63;
    const int n0 = blockIdx.x * 16;                 // 64 m-tiles
    const int o0 = blockIdx.y * 16;                 // 8 o-tiles

    const int mo = lane & 15;
    const int q  = lane >> 4;
    const u16* pA = gBas + (size_t)(n0 + mo) * KTOT;
    const u16* pB = gWp  + (size_t)(o0 + mo) * KTOT;

    f32x4 acc = {0.0f, 0.0f, 0.0f, 0.0f};
    #pragma unroll
    for (int s = 0; s < 2; ++s) {
        const int S = wave * 2 + s;                 // global K-step 0..31
        const int off = S * 32 + q * 8;             // elem offset, 16B aligned
        bf16x8 af = *(const bf16x8*)(pA + off);
        bf16x8 bf = *(const bf16x8*)(pB + off);
        acc = __builtin_amdgcn_mfma_f32_16x16x32_bf16(af, bf, acc, 0, 0, 0);
    }

    #pragma unroll
    for (int r = 0; r < 4; ++r)
        sC[wave * 256 + (q * 4 + r) * 16 + mo] = acc[r];
    __syncthreads();

    if (tid < 256) {
        const int row = tid >> 4, col = tid & 15;
        float v = sC[tid];
        #pragma unroll
        for (int w = 1; w < 16; ++w) v += sC[w * 256 + tid];
        out[(n0 + row) * DOUT + o0 + col] = v + bias[o0 + col];
    }
}

extern "C" void kernel_launch(void* const* d_in, const int* in_sizes, int n_in,
                              void* d_out, int out_size, void* d_ws, size_t ws_size,
                              hipStream_t stream) {
    const float* x       = (const float*)d_in[0];
    const float* coeffs  = (const float*)d_in[1];
    const float* weights = (const float*)d_in[2];
    const float* bias    = (const float*)d_in[3];
    float* out = (float*)d_out;
    const int N = in_sizes[0] / DIN;                // 1024

    u16* gBas = (u16*)d_ws;                         // N*128*8 bf16 = 2 MB
    u16* gWp  = gBas + (size_t)N * DIN * 8;         // 128*128*8 bf16 = 256 KB
    const int nBasis = N * DIN;
    const int nTot   = nBasis + DOUT * DIN;         // 147456 = 144*1024

    kan_pre<<<dim3((nTot + 1023) / 1024), 1024, 0, stream>>>(
        x, coeffs, weights, gBas, gWp, nBasis);

    dim3 grid(N / 16, DOUT / 16);                   // 64 x 8 = 512 blocks
    kan_mm<<<grid, 1024, 0, stream>>>(gBas, gWp, bias, out);
}

// Round 2
// 61.402 us; speedup vs baseline: 1.0703x; 1.0703x over previous
//
#include <hip/hip_runtime.h>
#include <hip/hip_bf16.h>
#include <stdint.h>

// KAN layer: out[n,o] = sum_j w[o,j] * spline(x[n,j]; coeffs[o,j,:]) + bias[o]
// N=1024, D_IN=128, D_OUT=128, K=8, Catmull-Rom, uniform grid [-1,1].
// fp32 in/out (proven R1/R2/R4).
//
// R13 POST-MORTEM: 2-kernel split = +3.05us. Extra graph node (~3us) >
// entire phase-1 dedup savings; stay at ONE launch forever.
//
// R14 (this): R12 fused structure +
//  - branchless pack-shift basis build: the 4 Catmull-Rom weights are a
//    CONTIGUOUS run at slot max(idx-1,0) (edge merges b0+b1 / b2+b3 in
//    fp32, bit-identical to R12's accumulate). cvt 4x bf16 -> pack u64 ->
//    128-bit shift by 16*p. Replaces the runtime-indexed r[8] scatter
//    (rule-#20: dynamic index => scratch or ~32-op cndmask chains).
//  - sC gets its own 16KB (no alias): LDS 32+32+16 = 80KB = exactly
//    2 blocks/CU, and the middle __syncthreads() is deleted (3 -> 2).
//  - __launch_bounds__(1024,8): pin VGPR<=64 so 32 waves/CU holds.
//
// MFMA 16x16x32 bf16 (R5..R12-verified): A/B-frag lane (mo=lane&15,
// q=lane>>4) holds [mo][k=32S+8q+kk]; C/D: col=lane&15, row=(lane>>4)*4+reg.

#define DIN 128
#define DOUT 128
#define KTOT 1024

typedef unsigned int u32;
typedef unsigned long long u64;
typedef unsigned short u16;
typedef __attribute__((ext_vector_type(8))) short bf16x8;
typedef __attribute__((ext_vector_type(4))) float f32x4;

union H8 { u16 s[8]; uint4 v; };

__device__ __forceinline__ u16 f2b(float f) {
    union { __hip_bfloat16 h; u16 u; } c;
    c.h = __float2bfloat16(f);   // RNE
    return c.u;
}

__global__ __launch_bounds__(1024, 8) void kan_fused(
    const float* __restrict__ x, const float* __restrict__ coeffs,
    const float* __restrict__ weights, const float* __restrict__ bias,
    float* __restrict__ out)
{
    __shared__ __align__(16) u16 sBas[16 * KTOT];   // 32 KB
    __shared__ __align__(16) u16 sWp [16 * KTOT];   // 32 KB
    __shared__ __align__(16) float sC[16 * 256];    // 16 KB (own space now)

    const int tid  = threadIdx.x;
    const int wave = tid >> 6;                      // 0..15
    const int lane = tid & 63;
    const int n0 = blockIdx.x * 16;                 // 64 m-tiles
    const int o0 = blockIdx.y * 16;                 // 8 o-tiles

    // ---- Phase 1a: basis tile. 2048 tasks (row,j), coalesced x reads ----
    #pragma unroll
    for (int it = 0; it < 2; ++it) {
        const int task = tid + it * 1024;           // row*128 + j
        const int row = task >> 7;
        const int j = task & 127;
        float xv = x[n0 * DIN + task];              // consecutive floats
        xv = fminf(fmaxf(xv, -1.0f), 1.0f);
        const float t = (xv + 1.0f) * 3.5f;         // h = 2/7
        int idx = (int)t; idx = idx > 6 ? 6 : idx;  // t>=0: trunc==floor
        const float u = t - (float)idx;
        const float u2 = u * u, u3 = u2 * u;
        const float b0 = 0.5f * (-u3 + 2.0f * u2 - u);
        const float b1 = 0.5f * (3.0f * u3 - 5.0f * u2 + 2.0f);
        const float b2 = 0.5f * (-3.0f * u3 + 4.0f * u2 + u);
        const float b3 = 0.5f * (u3 - u2);
        // Contiguous-run form of the clipped scatter (fp32 merges first,
        // bit-identical to accumulate-then-convert):
        //   idx==0: [b0+b1, b2, b3]      at slot 0
        //   1..5 :  [b0, b1, b2, b3]     at slot idx-1
        //   idx==6: [b0, b1, b2+b3, (b3 shifted out)] at slot 5
        const bool e0 = (idx == 0), e6 = (idx == 6);
        const float m0 = e0 ? b0 + b1 : b0;
        const float m1 = e0 ? b2 : b1;
        const float m2 = e0 ? b3 : (e6 ? b2 + b3 : b2);
        const float m3 = e0 ? 0.0f : b3;
        const u32 lo32 = (u32)f2b(m0) | ((u32)f2b(m1) << 16);
        const u32 hi32 = (u32)f2b(m2) | ((u32)f2b(m3) << 16);
        const u64 q64 = ((u64)hi32 << 32) | lo32;
        const int sh = e0 ? 0 : (idx - 1) * 16;     // 0..80 bits
        unsigned __int128 v = (unsigned __int128)q64 << sh;
        uint4 stv;
        stv.x = (u32)v;
        stv.y = (u32)(v >> 32);
        stv.z = (u32)(v >> 64);
        stv.w = (u32)(v >> 96);
        const int uu = j ^ (row & 7);               // swizzled 16B unit
        *(uint4*)(sBas + row * KTOT + uu * 8) = stv;
    }

    // ---- Phase 1b: W' tile. 2048 tasks (o,j), coalesced 32B/lane ----
    #pragma unroll
    for (int it = 0; it < 2; ++it) {
        const int task = tid + it * 1024;           // o*128 + j
        const int o = task >> 7;
        const int j = task & 127;
        const float wv = weights[o0 * DIN + task];  // consecutive floats
        const float4 c0 = *(const float4*)(coeffs + o0 * KTOT + task * 8);
        const float4 c1 = *(const float4*)(coeffs + o0 * KTOT + task * 8 + 4);
        H8 h;
        h.s[0] = f2b(c0.x * wv); h.s[1] = f2b(c0.y * wv);
        h.s[2] = f2b(c0.z * wv); h.s[3] = f2b(c0.w * wv);
        h.s[4] = f2b(c1.x * wv); h.s[5] = f2b(c1.y * wv);
        h.s[6] = f2b(c1.z * wv); h.s[7] = f2b(c1.w * wv);
        const int uu = j ^ (o & 7);
        *(uint4*)(sWp + o * KTOT + uu * 8) = h.v;
    }
    __syncthreads();

    // ---- Phase 2: pure LDS MFMA, wave = K-sixteenth (2 steps) ----
    const int mo = lane & 15;
    const int q  = lane >> 4;
    const int sw = mo & 7;                          // read-side swizzle
    f32x4 acc = {0.0f, 0.0f, 0.0f, 0.0f};
    #pragma unroll
    for (int s = 0; s < 2; ++s) {
        const int S = wave * 2 + s;                 // global K-step
        const int uu = (S * 4 + q) ^ sw;            // 16B unit
        bf16x8 af = *(const bf16x8*)(sBas + mo * KTOT + uu * 8);
        bf16x8 bf = *(const bf16x8*)(sWp  + mo * KTOT + uu * 8);
        acc = __builtin_amdgcn_mfma_f32_16x16x32_bf16(af, bf, acc, 0, 0, 0);
    }
    // sC is its own LDS region now -> no barrier needed before writing it.

    // ---- Phase 3: 16-way reduce + bias + store ----
    #pragma unroll
    for (int r = 0; r < 4; ++r)
        sC[wave * 256 + (q * 4 + r) * 16 + mo] = acc[r];
    __syncthreads();

    if (tid < 256) {
        const int row = tid >> 4, col = tid & 15;
        float v = sC[tid];
        #pragma unroll
        for (int w = 1; w < 16; ++w) v += sC[w * 256 + tid];
        out[(n0 + row) * DOUT + o0 + col] = v + bias[o0 + col];
    }
}

extern "C" void kernel_launch(void* const* d_in, const int* in_sizes, int n_in,
                              void* d_out, int out_size, void* d_ws, size_t ws_size,
                              hipStream_t stream) {
    const float* x       = (const float*)d_in[0];
    const float* coeffs  = (const float*)d_in[1];
    const float* weights = (const float*)d_in[2];
    const float* bias    = (const float*)d_in[3];
    float* out = (float*)d_out;
    const int N = in_sizes[0] / DIN;                // 1024
    dim3 grid(N / 16, DOUT / 16);                   // 64 x 8 = 512 blocks
    kan_fused<<<grid, 1024, 0, stream>>>(x, coeffs, weights, bias, out);
}